// Round 7
// baseline (788.988 us; speedup 1.0000x reference)
//
#include <hip/hip_runtime.h>
#include <math.h>

#define ZDIM 128
#define HDIM 100
#define JP   52          // padded half-width: 50 used + 2 zero-pad = 13 float4, 16B-aligned stride
#define JP4  (JP / 4)

// Repack weights for the pair-split kernel (zero-padded, 16B-aligned half-rows):
//   w1p[(k*2+h)*JP + j] = w1[(h*50+j)*ZDIM + k]   (j<50, else 0)   [128][2][52]
//   w2p[(i*2+h)*JP + j] = w2[i*HDIM + h*50 + j]   (j<50, else 0)   [100][2][52]
//   w3t[i*9 + r]        = w3[r*HDIM + i]                           [100][9]
__global__ void prep_pack(const float* __restrict__ w1,
                          const float* __restrict__ w2,
                          const float* __restrict__ w3,
                          float* __restrict__ w1p,
                          float* __restrict__ w2p,
                          float* __restrict__ w3t) {
    int idx = blockIdx.x * blockDim.x + threadIdx.x;
    if (idx < ZDIM * 2 * JP) {
        int k = idx / (2 * JP);
        int r = idx - k * 2 * JP;
        int h = r / JP;
        int j = r - h * JP;
        w1p[idx] = (j < 50) ? w1[(size_t)(h * 50 + j) * ZDIM + k] : 0.0f;
    }
    if (idx < HDIM * 2 * JP) {
        int i = idx / (2 * JP);
        int r = idx - i * 2 * JP;
        int h = r / JP;
        int j = r - h * JP;
        w2p[idx] = (j < 50) ? w2[(size_t)i * HDIM + h * 50 + j] : 0.0f;
    }
    if (idx < HDIM * 9) {
        int i = idx / 9;
        int r = idx - i * 9;
        w3t[idx] = w3[(size_t)r * HDIM + i];
    }
}

// Fast tanh: tanh(v) = (e-1)/(e+1), e = exp(2v). |v| <~ 15 here -> no overflow;
// err ~3e-7 abs, far below the pipeline's fp32 noise.
__device__ __forceinline__ float fast_tanh(float v) {
    float e = __expf(2.0f * v);
    return (e - 1.0f) / (e + 1.0f);
}

// fp64 polar decomposition (Higham scaled Newton, 8 iters) shared by both kernels.
// X <- 0.5*(g*X + (1/g)*X^{-T});  X^{-T} = cof(X)/det(X);
// g = (||X^{-1}||_F/||X||_F)^{1/2}. Converges to U V^T (reflections preserved).
__device__ __forceinline__ void polar3x3(const float mr[9], double X[9]) {
    #pragma unroll
    for (int r = 0; r < 9; ++r) X[r] = (double)mr[r];
    #pragma unroll 1
    for (int it = 0; it < 8; ++it) {
        double C00 = X[4]*X[8] - X[5]*X[7];
        double C01 = X[5]*X[6] - X[3]*X[8];
        double C02 = X[3]*X[7] - X[4]*X[6];
        double C10 = X[2]*X[7] - X[1]*X[8];
        double C11 = X[0]*X[8] - X[2]*X[6];
        double C12 = X[1]*X[6] - X[0]*X[7];
        double C20 = X[1]*X[5] - X[2]*X[4];
        double C21 = X[2]*X[3] - X[0]*X[5];
        double C22 = X[0]*X[4] - X[1]*X[3];
        double det = X[0]*C00 + X[1]*C01 + X[2]*C02;
        double adet = fabs(det);
        adet = adet < 1e-300 ? 1e-300 : adet;
        double sdet = (det < 0.0) ? -adet : adet;
        double nf2 = X[0]*X[0]+X[1]*X[1]+X[2]*X[2]+X[3]*X[3]+X[4]*X[4]
                   + X[5]*X[5]+X[6]*X[6]+X[7]*X[7]+X[8]*X[8];
        double nc2 = C00*C00+C01*C01+C02*C02+C10*C10+C11*C11
                   + C12*C12+C20*C20+C21*C21+C22*C22;
        double g = sqrt(sqrt(nc2 / nf2) / adet);
        double a = 0.5 * g;
        double b = 0.5 / (g * sdet);
        double Y0 = a*X[0] + b*C00, Y1 = a*X[1] + b*C01, Y2 = a*X[2] + b*C02;
        double Y3 = a*X[3] + b*C10, Y4 = a*X[4] + b*C11, Y5 = a*X[5] + b*C12;
        double Y6 = a*X[6] + b*C20, Y7 = a*X[7] + b*C21, Y8 = a*X[8] + b*C22;
        X[0]=Y0; X[1]=Y1; X[2]=Y2; X[3]=Y3; X[4]=Y4; X[5]=Y5; X[6]=Y6; X[7]=Y7; X[8]=Y8;
    }
}

// Pair-split main kernel: 2 threads per sample (lanes l, l^1), j-dimension 50/50.
// 524288 threads = 8192 waves = 8 waves/SIMD (hardware max) -- R3-R6 showed the
// kernel was stall-bound (VALUBusy*dur == VALU floor) at the grid-supplied
// 4 waves/SIMD; this doubles the latency-hiding TLP at flat per-CU VMEM count.
__global__ __launch_bounds__(256) void pose_split(
    const float* __restrict__ x,
    const float* __restrict__ b1,
    const float* __restrict__ b2,
    const float* __restrict__ b3,
    const float* __restrict__ w1p,  // [128][2][JP]
    const float* __restrict__ w2p,  // [100][2][JP]
    const float* __restrict__ w3t,  // [100][9]
    float* __restrict__ out,
    int nB)
{
    int tid = blockIdx.x * blockDim.x + threadIdx.x;
    int s = tid >> 1;        // sample
    int h = tid & 1;         // half: j in [h*50, h*50+50)
    if (s >= nB) return;

    const float4* xrow4 = reinterpret_cast<const float4*>(x + (size_t)s * ZDIM);
    const float4* w1p4 = reinterpret_cast<const float4*>(w1p) + (size_t)h * JP4;
    const float4* w2p4 = reinterpret_cast<const float4*>(w2p) + (size_t)h * JP4;

    // ---------- Layer 1 (half): acc[j'] = b1 + sum_k x[k]*w1[h*50+j'][k] ----------
    float acc[JP];
    #pragma unroll
    for (int j = 0; j < JP; ++j) acc[j] = (j < 50) ? b1[h * 50 + j] : 0.0f;

    float4 cur = xrow4[0];
    #pragma unroll 1
    for (int k4 = 0; k4 < ZDIM / 4; ++k4) {
        float4 nxt = xrow4[(k4 + 1) & (ZDIM / 4 - 1)];   // 1-deep prefetch
        const float xs[4] = { cur.x, cur.y, cur.z, cur.w };
        #pragma unroll
        for (int kk = 0; kk < 4; ++kk) {
            const int k = k4 * 4 + kk;
            const float4* wr = w1p4 + (size_t)k * (2 * JP4);
            const float xv = xs[kk];
            #pragma unroll
            for (int j4 = 0; j4 < JP4; ++j4) {
                float4 w = wr[j4];
                acc[4*j4+0] = fmaf(xv, w.x, acc[4*j4+0]);
                acc[4*j4+1] = fmaf(xv, w.y, acc[4*j4+1]);
                acc[4*j4+2] = fmaf(xv, w.z, acc[4*j4+2]);
                acc[4*j4+3] = fmaf(xv, w.w, acc[4*j4+3]);
            }
        }
        cur = nxt;
    }
    #pragma unroll
    for (int j = 0; j < JP; ++j) acc[j] = fmaxf(acc[j], 0.0f);   // pads stay 0

    // ---------- Layers 2+3: pair-combined dot per i, redundant tanh/L3 ----------
    float mr[9];
    #pragma unroll
    for (int r = 0; r < 9; ++r) mr[r] = b3[r];

    #pragma unroll 2
    for (int i = 0; i < HDIM; ++i) {
        const float4* wr = w2p4 + (size_t)i * (2 * JP4);
        float a0 = 0.f, a1 = 0.f, a2 = 0.f, a3 = 0.f;
        #pragma unroll
        for (int j4 = 0; j4 < JP4; ++j4) {
            float4 w = wr[j4];
            a0 = fmaf(w.x, acc[4*j4+0], a0);
            a1 = fmaf(w.y, acc[4*j4+1], a1);
            a2 = fmaf(w.z, acc[4*j4+2], a2);
            a3 = fmaf(w.w, acc[4*j4+3], a3);
        }
        float part = (a0 + a1) + (a2 + a3);
        float full = part + __shfl_xor(part, 1);         // combine pair halves
        float t = fast_tanh(full + b2[i]);
        #pragma unroll
        for (int r = 0; r < 9; ++r)
            mr[r] = fmaf(w3t[i * 9 + r], t, mr[r]);
    }

    // ---------- Polar (both lanes redundantly; identical results) ----------
    double X[9];
    polar3x3(mr, X);

    float* o = out + (size_t)s * 9;
    if (h == 0) {
        o[0] = (float)X[0]; o[1] = (float)X[1]; o[2] = (float)X[2];
        o[3] = (float)X[3]; o[4] = (float)X[4];
    } else {
        o[5] = (float)X[5]; o[6] = (float)X[6];
        o[7] = (float)X[7]; o[8] = (float)X[8];
    }
}

// Fallback (no workspace): R6-style 1 thread/sample, direct weight reads.
__global__ __launch_bounds__(256) void pose_simple(
    const float* __restrict__ x,
    const float* __restrict__ w1, const float* __restrict__ b1,
    const float* __restrict__ w2, const float* __restrict__ b2,
    const float* __restrict__ w3, const float* __restrict__ b3,
    float* __restrict__ out, int nB)
{
    int tid = blockIdx.x * blockDim.x + threadIdx.x;
    if (tid >= nB) return;
    const float* xrow = x + (size_t)tid * ZDIM;

    float h1[HDIM];
    #pragma unroll
    for (int j = 0; j < HDIM; ++j) h1[j] = b1[j];
    #pragma unroll 1
    for (int k = 0; k < ZDIM; ++k) {
        float xv = xrow[k];
        #pragma unroll
        for (int j = 0; j < HDIM; ++j)
            h1[j] = fmaf(xv, w1[(size_t)j * ZDIM + k], h1[j]);
    }
    #pragma unroll
    for (int j = 0; j < HDIM; ++j) h1[j] = fmaxf(h1[j], 0.0f);

    float mr[9];
    #pragma unroll
    for (int r = 0; r < 9; ++r) mr[r] = b3[r];
    #pragma unroll 1
    for (int i = 0; i < HDIM; ++i) {
        const float* w2row = w2 + (size_t)i * HDIM;
        float a0 = 0.f, a1 = 0.f, a2 = 0.f, a3 = 0.f;
        #pragma unroll
        for (int j = 0; j < HDIM; j += 4) {
            a0 = fmaf(w2row[j + 0], h1[j + 0], a0);
            a1 = fmaf(w2row[j + 1], h1[j + 1], a1);
            a2 = fmaf(w2row[j + 2], h1[j + 2], a2);
            a3 = fmaf(w2row[j + 3], h1[j + 3], a3);
        }
        float t = fast_tanh((a0 + a1) + (a2 + a3) + b2[i]);
        #pragma unroll
        for (int r = 0; r < 9; ++r)
            mr[r] = fmaf(w3[(size_t)r * HDIM + i], t, mr[r]);
    }

    double X[9];
    polar3x3(mr, X);
    float* o = out + (size_t)tid * 9;
    #pragma unroll
    for (int r = 0; r < 9; ++r) o[r] = (float)X[r];
}

extern "C" void kernel_launch(void* const* d_in, const int* in_sizes, int n_in,
                              void* d_out, int out_size, void* d_ws, size_t ws_size,
                              hipStream_t stream) {
    const float* x  = (const float*)d_in[0];
    const float* w1 = (const float*)d_in[1];
    const float* b1 = (const float*)d_in[2];
    const float* w2 = (const float*)d_in[3];
    const float* b2 = (const float*)d_in[4];
    const float* w3 = (const float*)d_in[5];
    const float* b3 = (const float*)d_in[6];
    float* out = (float*)d_out;

    int nB = in_sizes[0] / ZDIM;

    const size_t n_w1p = (size_t)ZDIM * 2 * JP;     // 13312
    const size_t n_w2p = (size_t)HDIM * 2 * JP;     // 10400
    const size_t n_w3t = (size_t)HDIM * 9;          // 900
    const size_t need  = (n_w1p + n_w2p + n_w3t) * sizeof(float);

    if (ws_size >= need) {
        float* w1p = (float*)d_ws;
        float* w2p = w1p + n_w1p;
        float* w3t = w2p + n_w2p;

        int prep_n = (int)n_w1p;                     // covers all three ranges
        prep_pack<<<(prep_n + 255) / 256, 256, 0, stream>>>(w1, w2, w3, w1p, w2p, w3t);

        long long threads = 2LL * nB;
        dim3 grid((unsigned)((threads + 255) / 256));
        pose_split<<<grid, 256, 0, stream>>>(x, b1, b2, b3, w1p, w2p, w3t, out, nB);
    } else {
        dim3 grid((nB + 255) / 256);
        pose_simple<<<grid, 256, 0, stream>>>(x, w1, b1, w2, b2, w3, b3, out, nB);
    }
}

// Round 9
// 424.442 us; speedup vs baseline: 1.8589x; 1.8589x over previous
//
#include <hip/hip_runtime.h>
#include <math.h>

#define ZDIM 128
#define HDIM 100
#define NPW  (112 * 128)      // elements per padded weight plane
#define LDSW 132              // LDS row stride (f32): 132 mod 32 = 4 -> spread banks; 16B-aligned rows

typedef __attribute__((ext_vector_type(8))) short bf16x8;   // 8 bf16 in 4 VGPRs (guide-verified typing)
typedef __attribute__((ext_vector_type(4))) float f32x4;

// ---------- bf16 split helpers (round-to-nearest-even) ----------
__device__ __host__ __forceinline__ unsigned short bf16_rne(float f) {
    unsigned u = __float_as_uint(f);
    unsigned r = u + 0x7FFFu + ((u >> 16) & 1u);
    return (unsigned short)(r >> 16);
}
__device__ __host__ __forceinline__ float bf16_back(unsigned short h) {
    return __uint_as_float(((unsigned)h) << 16);
}

// Fast tanh: tanh(v) = (e-1)/(e+1), e = exp(2v). |v| bounded here; err ~3e-7.
__device__ __forceinline__ float fast_tanh(float v) {
    float e = __expf(2.0f * v);
    return (e - 1.0f) / (e + 1.0f);
}

// fp64 polar (Higham scaled Newton, 8 iters) — proven in R4-R7.
__device__ __forceinline__ void polar3x3(const float mr[9], double X[9]) {
    #pragma unroll
    for (int r = 0; r < 9; ++r) X[r] = (double)mr[r];
    #pragma unroll 1
    for (int it = 0; it < 8; ++it) {
        double C00 = X[4]*X[8] - X[5]*X[7];
        double C01 = X[5]*X[6] - X[3]*X[8];
        double C02 = X[3]*X[7] - X[4]*X[6];
        double C10 = X[2]*X[7] - X[1]*X[8];
        double C11 = X[0]*X[8] - X[2]*X[6];
        double C12 = X[1]*X[6] - X[0]*X[7];
        double C20 = X[1]*X[5] - X[2]*X[4];
        double C21 = X[2]*X[3] - X[0]*X[5];
        double C22 = X[0]*X[4] - X[1]*X[3];
        double det = X[0]*C00 + X[1]*C01 + X[2]*C02;
        double adet = fabs(det);
        adet = adet < 1e-300 ? 1e-300 : adet;
        double sdet = (det < 0.0) ? -adet : adet;
        double nf2 = X[0]*X[0]+X[1]*X[1]+X[2]*X[2]+X[3]*X[3]+X[4]*X[4]
                   + X[5]*X[5]+X[6]*X[6]+X[7]*X[7]+X[8]*X[8];
        double nc2 = C00*C00+C01*C01+C02*C02+C10*C10+C11*C11
                   + C12*C12+C20*C20+C21*C21+C22*C22;
        double g = sqrt(sqrt(nc2 / nf2) / adet);
        double a = 0.5 * g;
        double b = 0.5 / (g * sdet);
        double Y0 = a*X[0] + b*C00, Y1 = a*X[1] + b*C01, Y2 = a*X[2] + b*C02;
        double Y3 = a*X[3] + b*C10, Y4 = a*X[4] + b*C11, Y5 = a*X[5] + b*C12;
        double Y6 = a*X[6] + b*C20, Y7 = a*X[7] + b*C21, Y8 = a*X[8] + b*C22;
        X[0]=Y0; X[1]=Y1; X[2]=Y2; X[3]=Y3; X[4]=Y4; X[5]=Y5; X[6]=Y6; X[7]=Y7; X[8]=Y8;
    }
}

// ---------- Prep: split weights into bf16x3 planes, pad N to 112 / K to 128 ----------
// w1p[p][col j][k] = plane_p(w1[j][k])           (j<100 else 0)         [3][112][128] bf16
// w2p[p][col i][k=j] = plane_p(w2[i][j])         (i<100 && j<100 else 0)[3][112][128] bf16
// w3p[r][i] fp32 padded [9][112];  b1p/b2p fp32 padded [112] (pad 0)
__global__ void prep_split(const float* __restrict__ w1, const float* __restrict__ w2,
                           const float* __restrict__ w3, const float* __restrict__ b1,
                           const float* __restrict__ b2,
                           unsigned short* __restrict__ w1p, unsigned short* __restrict__ w2p,
                           float* __restrict__ w3p, float* __restrict__ b1p,
                           float* __restrict__ b2p) {
    int idx = blockIdx.x * blockDim.x + threadIdx.x;
    if (idx < NPW) {
        int col = idx >> 7;          // 0..111
        int k   = idx & 127;         // 0..127
        float w = (col < HDIM) ? w1[(size_t)col * ZDIM + k] : 0.0f;
        unsigned short e1 = bf16_rne(w);  float r1 = w - bf16_back(e1);
        unsigned short e2 = bf16_rne(r1); float r2 = r1 - bf16_back(e2);
        unsigned short e3 = bf16_rne(r2);
        w1p[0*NPW + idx] = e1; w1p[1*NPW + idx] = e2; w1p[2*NPW + idx] = e3;

        float v = (col < HDIM && k < HDIM) ? w2[(size_t)col * HDIM + k] : 0.0f;
        unsigned short f1 = bf16_rne(v);  float s1 = v - bf16_back(f1);
        unsigned short f2 = bf16_rne(s1); float s2 = s1 - bf16_back(f2);
        unsigned short f3 = bf16_rne(s2);
        w2p[0*NPW + idx] = f1; w2p[1*NPW + idx] = f2; w2p[2*NPW + idx] = f3;
    }
    if (idx < 9 * 112) {
        int r = idx / 112, i = idx - r * 112;
        w3p[idx] = (i < HDIM) ? w3[(size_t)r * HDIM + i] : 0.0f;
    }
    if (idx < 112) {
        b1p[idx] = (idx < HDIM) ? b1[idx] : 0.0f;
        b2p[idx] = (idx < HDIM) ? b2[idx] : 0.0f;
    }
}

// ---------- Main: MFMA layers 1+2 (bf16x3), VALU layer 3, fp64 polar ----------
// 1 wave = 64 samples = 4 M-tiles of 16. Per-wave private LDS (no barriers).
// MFMA 16x16x32 conventions: A/B packed with the SAME (lane&15, lane>>4, elem)
// convention (any error in the assumed lane->k map cancels in the contraction);
// C/D (measured, m89/m91): col=lane&15, row=4*(lane>>4)+reg.
__global__ __launch_bounds__(256) void pose_mfma(
    const float* __restrict__ x,
    const unsigned short* __restrict__ w1p,
    const unsigned short* __restrict__ w2p,
    const float* __restrict__ w3p,
    const float* __restrict__ b1p,
    const float* __restrict__ b2p,
    const float* __restrict__ b3,   // [9] -- R8 bug: this was missing entirely
    float* __restrict__ out)
{
    __shared__ float hbuf_all[4][16 * LDSW];      // 33792 B -> 4 blocks/CU
    const int lane = threadIdx.x & 63;
    const int wid  = threadIdx.x >> 6;
    float* hb = hbuf_all[wid];

    const long long base = ((long long)blockIdx.x * 4 + wid) * 64;
    const int lrow = lane & 15;      // A-row / B-col / C-col slot
    const int lgrp = lane >> 4;      // k-group / C row-group

    float myM[9] = {0,0,0,0,0,0,0,0,0};

    #pragma unroll 1
    for (int t = 0; t < 4; ++t) {
        const float* xrow = x + (size_t)(base + t * 16 + lrow) * ZDIM;

        // ================= Layer 1: C = x @ w1^T (MFMA, bf16x3) =================
        f32x4 C1[7];
        #pragma unroll
        for (int n = 0; n < 7; ++n) C1[n] = (f32x4){0.f, 0.f, 0.f, 0.f};

        #pragma unroll 1
        for (int kt = 0; kt < 4; ++kt) {
            const int k0 = kt * 32 + lgrp * 8;
            const float4 xa = *reinterpret_cast<const float4*>(xrow + k0);
            const float4 xb = *reinterpret_cast<const float4*>(xrow + k0 + 4);
            const float xr[8] = { xa.x, xa.y, xa.z, xa.w, xb.x, xb.y, xb.z, xb.w };
            bf16x8 A1, A2, A3;
            #pragma unroll
            for (int e = 0; e < 8; ++e) {
                unsigned short e1 = bf16_rne(xr[e]); float r1 = xr[e] - bf16_back(e1);
                unsigned short e2 = bf16_rne(r1);    float r2 = r1   - bf16_back(e2);
                unsigned short e3 = bf16_rne(r2);
                A1[e] = (short)e1; A2[e] = (short)e2; A3[e] = (short)e3;
            }
            #pragma unroll
            for (int n = 0; n < 7; ++n) {
                const unsigned short* bp = w1p + ((size_t)(n * 16 + lrow) * 128 + k0);
                bf16x8 B1 = *reinterpret_cast<const bf16x8*>(bp);
                bf16x8 B2 = *reinterpret_cast<const bf16x8*>(bp + NPW);
                bf16x8 B3 = *reinterpret_cast<const bf16x8*>(bp + 2 * NPW);
                C1[n] = __builtin_amdgcn_mfma_f32_16x16x32_bf16(A1, B1, C1[n], 0, 0, 0);
                C1[n] = __builtin_amdgcn_mfma_f32_16x16x32_bf16(A1, B2, C1[n], 0, 0, 0);
                C1[n] = __builtin_amdgcn_mfma_f32_16x16x32_bf16(A2, B1, C1[n], 0, 0, 0);
                C1[n] = __builtin_amdgcn_mfma_f32_16x16x32_bf16(A1, B3, C1[n], 0, 0, 0);
                C1[n] = __builtin_amdgcn_mfma_f32_16x16x32_bf16(A2, B2, C1[n], 0, 0, 0);
                C1[n] = __builtin_amdgcn_mfma_f32_16x16x32_bf16(A3, B1, C1[n], 0, 0, 0);
            }
        }

        // bias + relu + write h1 to LDS, XOR-swizzled: col' = col ^ ((row&3)<<3)
        #pragma unroll
        for (int n = 0; n < 7; ++n) {
            float bv = b1p[n * 16 + lrow];
            #pragma unroll
            for (int q = 0; q < 4; ++q) {
                int row = lgrp * 4 + q;
                int col = n * 16 + lrow;
                hb[row * LDSW + (col ^ ((row & 3) << 3))] = fmaxf(C1[n][q] + bv, 0.0f);
            }
        }
        #pragma unroll
        for (int q = 0; q < 4; ++q) {            // zero pad cols 112..127 (K-pad for L2)
            int row = lgrp * 4 + q;
            int col = 112 + lrow;
            hb[row * LDSW + (col ^ ((row & 3) << 3))] = 0.0f;
        }

        // ================= Layer 2: C2 = h1 @ w2^T (MFMA, bf16x3) =================
        f32x4 C2[7];
        #pragma unroll
        for (int n = 0; n < 7; ++n) C2[n] = (f32x4){0.f, 0.f, 0.f, 0.f};

        #pragma unroll 1
        for (int kt = 0; kt < 4; ++kt) {
            const int col0 = kt * 32 + lgrp * 8;
            const int sc = col0 ^ ((lrow & 3) << 3);      // same XOR swizzle, row = lrow
            const float4 ha = *reinterpret_cast<const float4*>(hb + lrow * LDSW + sc);
            const float4 hbv = *reinterpret_cast<const float4*>(hb + lrow * LDSW + sc + 4);
            const float hr[8] = { ha.x, ha.y, ha.z, ha.w, hbv.x, hbv.y, hbv.z, hbv.w };
            bf16x8 A1, A2, A3;
            #pragma unroll
            for (int e = 0; e < 8; ++e) {
                unsigned short e1 = bf16_rne(hr[e]); float r1 = hr[e] - bf16_back(e1);
                unsigned short e2 = bf16_rne(r1);    float r2 = r1    - bf16_back(e2);
                unsigned short e3 = bf16_rne(r2);
                A1[e] = (short)e1; A2[e] = (short)e2; A3[e] = (short)e3;
            }
            #pragma unroll
            for (int n = 0; n < 7; ++n) {
                const unsigned short* bp = w2p + ((size_t)(n * 16 + lrow) * 128 + col0);
                bf16x8 B1 = *reinterpret_cast<const bf16x8*>(bp);
                bf16x8 B2 = *reinterpret_cast<const bf16x8*>(bp + NPW);
                bf16x8 B3 = *reinterpret_cast<const bf16x8*>(bp + 2 * NPW);
                C2[n] = __builtin_amdgcn_mfma_f32_16x16x32_bf16(A1, B1, C2[n], 0, 0, 0);
                C2[n] = __builtin_amdgcn_mfma_f32_16x16x32_bf16(A1, B2, C2[n], 0, 0, 0);
                C2[n] = __builtin_amdgcn_mfma_f32_16x16x32_bf16(A2, B1, C2[n], 0, 0, 0);
                C2[n] = __builtin_amdgcn_mfma_f32_16x16x32_bf16(A1, B3, C2[n], 0, 0, 0);
                C2[n] = __builtin_amdgcn_mfma_f32_16x16x32_bf16(A2, B2, C2[n], 0, 0, 0);
                C2[n] = __builtin_amdgcn_mfma_f32_16x16x32_bf16(A3, B1, C2[n], 0, 0, 0);
            }
        }

        // ============ tanh + Layer 3 partials (VALU): mp[q][r] over this lane's 7 cols ============
        float mp[4][9];
        #pragma unroll
        for (int q = 0; q < 4; ++q)
            #pragma unroll
            for (int r = 0; r < 9; ++r) mp[q][r] = 0.0f;

        #pragma unroll
        for (int n = 0; n < 7; ++n) {
            float bv = b2p[n * 16 + lrow];
            int colI = n * 16 + lrow;
            float w3c[9];
            #pragma unroll
            for (int r = 0; r < 9; ++r) w3c[r] = w3p[r * 112 + colI];
            #pragma unroll
            for (int q = 0; q < 4; ++q) {
                float tv = fast_tanh(C2[n][q] + bv);
                #pragma unroll
                for (int r = 0; r < 9; ++r) mp[q][r] = fmaf(w3c[r], tv, mp[q][r]);
            }
        }

        // 16-lane butterfly reduce (lanes sharing l>>4 hold the same 4 sample-rows)
        #pragma unroll
        for (int m = 1; m < 16; m <<= 1)
            #pragma unroll
            for (int q = 0; q < 4; ++q)
                #pragma unroll
                for (int r = 0; r < 9; ++r)
                    mp[q][r] += __shfl_xor(mp[q][r], m);

        // Lane keeps its one sample from this tile: tile t == (lane>>2)&3, q == lane&3.
        const bool keep = (((lane >> 2) & 3) == t);
        const int c = lane & 3;
        #pragma unroll
        for (int r = 0; r < 9; ++r) {
            float v = (c == 0) ? mp[0][r] : (c == 1) ? mp[1][r] : (c == 2) ? mp[2][r] : mp[3][r];
            myM[r] = keep ? v : myM[r];
        }
    }

    // ---------- add b3 (the R8 bug), then polar (fp64, proven) ----------
    #pragma unroll
    for (int r = 0; r < 9; ++r) myM[r] += b3[r];

    double X[9];
    polar3x3(myM, X);

    const long long samp = base + 16 * ((lane >> 2) & 3) + 4 * (lane >> 4) + (lane & 3);
    float* o = out + samp * 9;
    #pragma unroll
    for (int r = 0; r < 9; ++r) o[r] = (float)X[r];
}

// ---------- Fallback: proven R6-style 1 thread/sample VALU kernel ----------
__global__ __launch_bounds__(256) void pose_simple(
    const float* __restrict__ x,
    const float* __restrict__ w1, const float* __restrict__ b1,
    const float* __restrict__ w2, const float* __restrict__ b2,
    const float* __restrict__ w3, const float* __restrict__ b3,
    float* __restrict__ out, int nB)
{
    int tid = blockIdx.x * blockDim.x + threadIdx.x;
    if (tid >= nB) return;
    const float* xrow = x + (size_t)tid * ZDIM;

    float h1[HDIM];
    #pragma unroll
    for (int j = 0; j < HDIM; ++j) h1[j] = b1[j];
    #pragma unroll 1
    for (int k = 0; k < ZDIM; ++k) {
        float xv = xrow[k];
        #pragma unroll
        for (int j = 0; j < HDIM; ++j)
            h1[j] = fmaf(xv, w1[(size_t)j * ZDIM + k], h1[j]);
    }
    #pragma unroll
    for (int j = 0; j < HDIM; ++j) h1[j] = fmaxf(h1[j], 0.0f);

    float mr[9];
    #pragma unroll
    for (int r = 0; r < 9; ++r) mr[r] = b3[r];
    #pragma unroll 1
    for (int i = 0; i < HDIM; ++i) {
        const float* w2row = w2 + (size_t)i * HDIM;
        float a0 = 0.f, a1 = 0.f, a2 = 0.f, a3 = 0.f;
        #pragma unroll
        for (int j = 0; j < HDIM; j += 4) {
            a0 = fmaf(w2row[j + 0], h1[j + 0], a0);
            a1 = fmaf(w2row[j + 1], h1[j + 1], a1);
            a2 = fmaf(w2row[j + 2], h1[j + 2], a2);
            a3 = fmaf(w2row[j + 3], h1[j + 3], a3);
        }
        float tv = fast_tanh((a0 + a1) + (a2 + a3) + b2[i]);
        #pragma unroll
        for (int r = 0; r < 9; ++r)
            mr[r] = fmaf(w3[(size_t)r * HDIM + i], tv, mr[r]);
    }

    double X[9];
    polar3x3(mr, X);
    float* o = out + (size_t)tid * 9;
    #pragma unroll
    for (int r = 0; r < 9; ++r) o[r] = (float)X[r];
}

extern "C" void kernel_launch(void* const* d_in, const int* in_sizes, int n_in,
                              void* d_out, int out_size, void* d_ws, size_t ws_size,
                              hipStream_t stream) {
    const float* x  = (const float*)d_in[0];
    const float* w1 = (const float*)d_in[1];
    const float* b1 = (const float*)d_in[2];
    const float* w2 = (const float*)d_in[3];
    const float* b2 = (const float*)d_in[4];
    const float* w3 = (const float*)d_in[5];
    const float* b3 = (const float*)d_in[6];
    float* out = (float*)d_out;

    int nB = in_sizes[0] / ZDIM;

    // ws layout (bytes): w1p[0..86016) w2p[86016..172032) w3p[..176064) b1p[..176512) b2p[..176960)
    const size_t off_w2p = (size_t)3 * NPW * sizeof(unsigned short);          // 86016
    const size_t off_w3p = off_w2p * 2;                                       // 172032
    const size_t off_b1p = off_w3p + (size_t)9 * 112 * sizeof(float);         // 176064
    const size_t off_b2p = off_b1p + 112 * sizeof(float);                     // 176512
    const size_t need    = off_b2p + 112 * sizeof(float);                     // 176960

    if (ws_size >= need && (nB % 256) == 0) {
        unsigned short* w1p = (unsigned short*)d_ws;
        unsigned short* w2p = (unsigned short*)((char*)d_ws + off_w2p);
        float* w3p = (float*)((char*)d_ws + off_w3p);
        float* b1p = (float*)((char*)d_ws + off_b1p);
        float* b2p = (float*)((char*)d_ws + off_b2p);

        prep_split<<<(NPW + 255) / 256, 256, 0, stream>>>(w1, w2, w3, b1, b2,
                                                          w1p, w2p, w3p, b1p, b2p);
        dim3 grid(nB / 256);   // 1024 blocks; 4 waves/block; 64 samples/wave
        pose_mfma<<<grid, 256, 0, stream>>>(x, w1p, w2p, w3p, b1p, b2p, b3, out);
    } else {
        dim3 grid((nB + 255) / 256);
        pose_simple<<<grid, 256, 0, stream>>>(x, w1, b1, w2, b2, w3, b3, out, nB);
    }
}

// Round 10
// 350.806 us; speedup vs baseline: 2.2491x; 1.2099x over previous
//
#include <hip/hip_runtime.h>
#include <math.h>

#define ZDIM 128
#define HDIM 100
#define NPW  (112 * 128)      // elements per padded w1/w2 plane
#define W3N  (16 * 128)       // elements per padded w3 plane (16 cols x 128 k)
#define LDSW 132              // LDS row stride (f32) for h-tiles
#define MSTR 12               // LDS row stride (f32) for the M bounce (3 x float4)

typedef __attribute__((ext_vector_type(8))) short bf16x8;   // 8 bf16 in 4 VGPRs
typedef __attribute__((ext_vector_type(4))) float f32x4;

// ---------- bf16 split helpers (round-to-nearest-even) ----------
__device__ __host__ __forceinline__ unsigned short bf16_rne(float f) {
    unsigned u = __float_as_uint(f);
    unsigned r = u + 0x7FFFu + ((u >> 16) & 1u);
    return (unsigned short)(r >> 16);
}
__device__ __host__ __forceinline__ float bf16_back(unsigned short h) {
    return __uint_as_float(((unsigned)h) << 16);
}

// Fast tanh: tanh(v) = (e-1)/(e+1), e = exp(2v). |v| bounded here; err ~3e-7.
__device__ __forceinline__ float fast_tanh(float v) {
    float e = __expf(2.0f * v);
    return (e - 1.0f) / (e + 1.0f);
}

// fp64 polar (Higham scaled Newton, 8 iters) — proven R4-R9.
__device__ __forceinline__ void polar3x3(const float mr[9], double X[9]) {
    #pragma unroll
    for (int r = 0; r < 9; ++r) X[r] = (double)mr[r];
    #pragma unroll 1
    for (int it = 0; it < 8; ++it) {
        double C00 = X[4]*X[8] - X[5]*X[7];
        double C01 = X[5]*X[6] - X[3]*X[8];
        double C02 = X[3]*X[7] - X[4]*X[6];
        double C10 = X[2]*X[7] - X[1]*X[8];
        double C11 = X[0]*X[8] - X[2]*X[6];
        double C12 = X[1]*X[6] - X[0]*X[7];
        double C20 = X[1]*X[5] - X[2]*X[4];
        double C21 = X[2]*X[3] - X[0]*X[5];
        double C22 = X[0]*X[4] - X[1]*X[3];
        double det = X[0]*C00 + X[1]*C01 + X[2]*C02;
        double adet = fabs(det);
        adet = adet < 1e-300 ? 1e-300 : adet;
        double sdet = (det < 0.0) ? -adet : adet;
        double nf2 = X[0]*X[0]+X[1]*X[1]+X[2]*X[2]+X[3]*X[3]+X[4]*X[4]
                   + X[5]*X[5]+X[6]*X[6]+X[7]*X[7]+X[8]*X[8];
        double nc2 = C00*C00+C01*C01+C02*C02+C10*C10+C11*C11
                   + C12*C12+C20*C20+C21*C21+C22*C22;
        double g = sqrt(sqrt(nc2 / nf2) / adet);
        double a = 0.5 * g;
        double b = 0.5 / (g * sdet);
        double Y0 = a*X[0] + b*C00, Y1 = a*X[1] + b*C01, Y2 = a*X[2] + b*C02;
        double Y3 = a*X[3] + b*C10, Y4 = a*X[4] + b*C11, Y5 = a*X[5] + b*C12;
        double Y6 = a*X[6] + b*C20, Y7 = a*X[7] + b*C21, Y8 = a*X[8] + b*C22;
        X[0]=Y0; X[1]=Y1; X[2]=Y2; X[3]=Y3; X[4]=Y4; X[5]=Y5; X[6]=Y6; X[7]=Y7; X[8]=Y8;
    }
}

// ---------- Prep: bf16x3 planes for w1, w2, w3; padded fp32 biases ----------
// w1p[p][col j][k] = plane_p(w1[j][k])   (j<100 else 0)            [3][112][128]
// w2p[p][col i][j] = plane_p(w2[i][j])   (i<100 && j<100 else 0)   [3][112][128]
// w3b[p][col r][i] = plane_p(w3[r][i])   (r<9  && i<100 else 0)    [3][16][128]
__global__ void prep_split(const float* __restrict__ w1, const float* __restrict__ w2,
                           const float* __restrict__ w3, const float* __restrict__ b1,
                           const float* __restrict__ b2, const float* __restrict__ b3,
                           unsigned short* __restrict__ w1p, unsigned short* __restrict__ w2p,
                           unsigned short* __restrict__ w3b,
                           float* __restrict__ b1p, float* __restrict__ b2p,
                           float* __restrict__ b3p) {
    int idx = blockIdx.x * blockDim.x + threadIdx.x;
    if (idx < NPW) {
        int col = idx >> 7;          // 0..111
        int k   = idx & 127;         // 0..127
        float w = (col < HDIM) ? w1[(size_t)col * ZDIM + k] : 0.0f;
        unsigned short e1 = bf16_rne(w);  float r1 = w - bf16_back(e1);
        unsigned short e2 = bf16_rne(r1); float r2 = r1 - bf16_back(e2);
        unsigned short e3 = bf16_rne(r2);
        w1p[0*NPW + idx] = e1; w1p[1*NPW + idx] = e2; w1p[2*NPW + idx] = e3;

        float v = (col < HDIM && k < HDIM) ? w2[(size_t)col * HDIM + k] : 0.0f;
        unsigned short f1 = bf16_rne(v);  float s1 = v - bf16_back(f1);
        unsigned short f2 = bf16_rne(s1); float s2 = s1 - bf16_back(f2);
        unsigned short f3 = bf16_rne(s2);
        w2p[0*NPW + idx] = f1; w2p[1*NPW + idx] = f2; w2p[2*NPW + idx] = f3;
    }
    if (idx < W3N) {
        int col = idx >> 7;          // 0..15 (w3 output row r)
        int k   = idx & 127;         // 0..127 (h2 index i)
        float v = (col < 9 && k < HDIM) ? w3[(size_t)col * HDIM + k] : 0.0f;
        unsigned short f1 = bf16_rne(v);  float s1 = v - bf16_back(f1);
        unsigned short f2 = bf16_rne(s1); float s2 = s1 - bf16_back(f2);
        unsigned short f3 = bf16_rne(s2);
        w3b[0*W3N + idx] = f1; w3b[1*W3N + idx] = f2; w3b[2*W3N + idx] = f3;
    }
    if (idx < 112) {
        b1p[idx] = (idx < HDIM) ? b1[idx] : 0.0f;
        b2p[idx] = (idx < HDIM) ? b2[idx] : 0.0f;
    }
    if (idx < 16) b3p[idx] = (idx < 9) ? b3[idx] : 0.0f;
}

// ---------- Main: 3 MFMA layers (bf16x3) + LDS transposes + fp64 polar ----------
// 1 wave = 64 samples = 4 M-tiles of 16. Per-wave private LDS, no barriers
// (DS pipe is in-order per wave; RAW/WAR chains proven in R9).
// 16x16x32 layouts: A/B packed with the same (lane&15, lane>>4, elem) convention;
// C/D (measured m89/m91): col=lane&15, row=4*(lane>>4)+reg.
// R9 lesson: the scalar layer-3 epilogue (mp[36]+butterfly) caused ~195MB of
// scratch spill -> layer 3 is now MFMA (one 16-col tile) + a 16x12 LDS bounce.
__global__ __launch_bounds__(256) void pose_mfma(
    const float* __restrict__ x,
    const unsigned short* __restrict__ w1p,
    const unsigned short* __restrict__ w2p,
    const unsigned short* __restrict__ w3b,
    const float* __restrict__ b1p,
    const float* __restrict__ b2p,
    const float* __restrict__ b3p,
    float* __restrict__ out)
{
    __shared__ float hbuf_all[4][16 * LDSW + 16 * MSTR];   // 36864 B -> 4 blocks/CU
    const int lane = threadIdx.x & 63;
    const int wid  = threadIdx.x >> 6;
    float* hb = hbuf_all[wid];
    float* mb = hb + 16 * LDSW;

    const long long base = ((long long)blockIdx.x * 4 + wid) * 64;
    const int lrow = lane & 15;      // A-row / B-col / C-col slot
    const int lgrp = lane >> 4;      // k-group / C row-group

    float myM[9] = {0,0,0,0,0,0,0,0,0};

    #pragma unroll 1
    for (int t = 0; t < 4; ++t) {
        const float* xrow = x + (size_t)(base + t * 16 + lrow) * ZDIM;

        // ================= Layer 1: C1 = x @ w1^T =================
        f32x4 C1[7];
        #pragma unroll
        for (int n = 0; n < 7; ++n) C1[n] = (f32x4){0.f, 0.f, 0.f, 0.f};

        #pragma unroll 1
        for (int kt = 0; kt < 4; ++kt) {
            const int k0 = kt * 32 + lgrp * 8;
            const float4 xa = *reinterpret_cast<const float4*>(xrow + k0);
            const float4 xb = *reinterpret_cast<const float4*>(xrow + k0 + 4);
            const float xr[8] = { xa.x, xa.y, xa.z, xa.w, xb.x, xb.y, xb.z, xb.w };
            bf16x8 A1, A2, A3;
            #pragma unroll
            for (int e = 0; e < 8; ++e) {
                unsigned short e1 = bf16_rne(xr[e]); float r1 = xr[e] - bf16_back(e1);
                unsigned short e2 = bf16_rne(r1);    float r2 = r1   - bf16_back(e2);
                unsigned short e3 = bf16_rne(r2);
                A1[e] = (short)e1; A2[e] = (short)e2; A3[e] = (short)e3;
            }
            #pragma unroll
            for (int n = 0; n < 7; ++n) {
                const unsigned short* bp = w1p + ((size_t)(n * 16 + lrow) * 128 + k0);
                bf16x8 B1 = *reinterpret_cast<const bf16x8*>(bp);
                bf16x8 B2 = *reinterpret_cast<const bf16x8*>(bp + NPW);
                bf16x8 B3 = *reinterpret_cast<const bf16x8*>(bp + 2 * NPW);
                C1[n] = __builtin_amdgcn_mfma_f32_16x16x32_bf16(A1, B1, C1[n], 0, 0, 0);
                C1[n] = __builtin_amdgcn_mfma_f32_16x16x32_bf16(A1, B2, C1[n], 0, 0, 0);
                C1[n] = __builtin_amdgcn_mfma_f32_16x16x32_bf16(A2, B1, C1[n], 0, 0, 0);
                C1[n] = __builtin_amdgcn_mfma_f32_16x16x32_bf16(A1, B3, C1[n], 0, 0, 0);
                C1[n] = __builtin_amdgcn_mfma_f32_16x16x32_bf16(A2, B2, C1[n], 0, 0, 0);
                C1[n] = __builtin_amdgcn_mfma_f32_16x16x32_bf16(A3, B1, C1[n], 0, 0, 0);
            }
        }

        // bias + relu + h1 -> LDS, swizzled: col' = col ^ ((row&3)<<3)
        #pragma unroll
        for (int n = 0; n < 7; ++n) {
            float bv = b1p[n * 16 + lrow];
            #pragma unroll
            for (int q = 0; q < 4; ++q) {
                int row = lgrp * 4 + q;
                int col = n * 16 + lrow;
                hb[row * LDSW + (col ^ ((row & 3) << 3))] = fmaxf(C1[n][q] + bv, 0.0f);
            }
        }
        #pragma unroll
        for (int q = 0; q < 4; ++q) {            // zero K-pad cols 112..127
            int row = lgrp * 4 + q;
            int col = 112 + lrow;
            hb[row * LDSW + (col ^ ((row & 3) << 3))] = 0.0f;
        }

        // ================= Layer 2: C2 = h1 @ w2^T =================
        f32x4 C2[7];
        #pragma unroll
        for (int n = 0; n < 7; ++n) C2[n] = (f32x4){0.f, 0.f, 0.f, 0.f};

        #pragma unroll 1
        for (int kt = 0; kt < 4; ++kt) {
            const int col0 = kt * 32 + lgrp * 8;
            const int sc = col0 ^ ((lrow & 3) << 3);
            const float4 ha = *reinterpret_cast<const float4*>(hb + lrow * LDSW + sc);
            const float4 hc = *reinterpret_cast<const float4*>(hb + lrow * LDSW + sc + 4);
            const float hr[8] = { ha.x, ha.y, ha.z, ha.w, hc.x, hc.y, hc.z, hc.w };
            bf16x8 A1, A2, A3;
            #pragma unroll
            for (int e = 0; e < 8; ++e) {
                unsigned short e1 = bf16_rne(hr[e]); float r1 = hr[e] - bf16_back(e1);
                unsigned short e2 = bf16_rne(r1);    float r2 = r1    - bf16_back(e2);
                unsigned short e3 = bf16_rne(r2);
                A1[e] = (short)e1; A2[e] = (short)e2; A3[e] = (short)e3;
            }
            #pragma unroll
            for (int n = 0; n < 7; ++n) {
                const unsigned short* bp = w2p + ((size_t)(n * 16 + lrow) * 128 + col0);
                bf16x8 B1 = *reinterpret_cast<const bf16x8*>(bp);
                bf16x8 B2 = *reinterpret_cast<const bf16x8*>(bp + NPW);
                bf16x8 B3 = *reinterpret_cast<const bf16x8*>(bp + 2 * NPW);
                C2[n] = __builtin_amdgcn_mfma_f32_16x16x32_bf16(A1, B1, C2[n], 0, 0, 0);
                C2[n] = __builtin_amdgcn_mfma_f32_16x16x32_bf16(A1, B2, C2[n], 0, 0, 0);
                C2[n] = __builtin_amdgcn_mfma_f32_16x16x32_bf16(A2, B1, C2[n], 0, 0, 0);
                C2[n] = __builtin_amdgcn_mfma_f32_16x16x32_bf16(A1, B3, C2[n], 0, 0, 0);
                C2[n] = __builtin_amdgcn_mfma_f32_16x16x32_bf16(A2, B2, C2[n], 0, 0, 0);
                C2[n] = __builtin_amdgcn_mfma_f32_16x16x32_bf16(A3, B1, C2[n], 0, 0, 0);
            }
        }

        // bias + tanh + h2 -> LDS (same swizzle; overwrites h1, in-order DS safe)
        #pragma unroll
        for (int n = 0; n < 7; ++n) {
            float bv = b2p[n * 16 + lrow];
            #pragma unroll
            for (int q = 0; q < 4; ++q) {
                int row = lgrp * 4 + q;
                int col = n * 16 + lrow;
                hb[row * LDSW + (col ^ ((row & 3) << 3))] = fast_tanh(C2[n][q] + bv);
            }
        }
        #pragma unroll
        for (int q = 0; q < 4; ++q) {
            int row = lgrp * 4 + q;
            int col = 112 + lrow;
            hb[row * LDSW + (col ^ ((row & 3) << 3))] = 0.0f;
        }

        // ================= Layer 3: C3 = h2 @ w3^T (one 16-col tile) =================
        f32x4 C3 = (f32x4){0.f, 0.f, 0.f, 0.f};
        #pragma unroll 1
        for (int kt = 0; kt < 4; ++kt) {
            const int col0 = kt * 32 + lgrp * 8;
            const int sc = col0 ^ ((lrow & 3) << 3);
            const float4 ha = *reinterpret_cast<const float4*>(hb + lrow * LDSW + sc);
            const float4 hc = *reinterpret_cast<const float4*>(hb + lrow * LDSW + sc + 4);
            const float hr[8] = { ha.x, ha.y, ha.z, ha.w, hc.x, hc.y, hc.z, hc.w };
            bf16x8 A1, A2, A3;
            #pragma unroll
            for (int e = 0; e < 8; ++e) {
                unsigned short e1 = bf16_rne(hr[e]); float r1 = hr[e] - bf16_back(e1);
                unsigned short e2 = bf16_rne(r1);    float r2 = r1    - bf16_back(e2);
                unsigned short e3 = bf16_rne(r2);
                A1[e] = (short)e1; A2[e] = (short)e2; A3[e] = (short)e3;
            }
            const unsigned short* bp = w3b + ((size_t)lrow * 128 + col0);
            bf16x8 B1 = *reinterpret_cast<const bf16x8*>(bp);
            bf16x8 B2 = *reinterpret_cast<const bf16x8*>(bp + W3N);
            bf16x8 B3 = *reinterpret_cast<const bf16x8*>(bp + 2 * W3N);
            C3 = __builtin_amdgcn_mfma_f32_16x16x32_bf16(A1, B1, C3, 0, 0, 0);
            C3 = __builtin_amdgcn_mfma_f32_16x16x32_bf16(A1, B2, C3, 0, 0, 0);
            C3 = __builtin_amdgcn_mfma_f32_16x16x32_bf16(A2, B1, C3, 0, 0, 0);
            C3 = __builtin_amdgcn_mfma_f32_16x16x32_bf16(A1, B3, C3, 0, 0, 0);
            C3 = __builtin_amdgcn_mfma_f32_16x16x32_bf16(A2, B2, C3, 0, 0, 0);
            C3 = __builtin_amdgcn_mfma_f32_16x16x32_bf16(A3, B1, C3, 0, 0, 0);
        }

        // M + b3 -> LDS bounce (col=lrow is the output index r; rows are samples)
        {
            float bv3 = b3p[lrow];
            if (lrow < 9) {
                #pragma unroll
                for (int q = 0; q < 4; ++q)
                    mb[(lgrp * 4 + q) * MSTR + lrow] = C3[q] + bv3;
            }
        }
        // Owner lanes of tile t collect their sample's 9 floats
        if (((lane >> 2) & 3) == t) {
            int row = 4 * (lane >> 4) + (lane & 3);
            const float4 m0 = *reinterpret_cast<const float4*>(mb + row * MSTR);
            const float4 m1 = *reinterpret_cast<const float4*>(mb + row * MSTR + 4);
            const float4 m2 = *reinterpret_cast<const float4*>(mb + row * MSTR + 8);
            myM[0] = m0.x; myM[1] = m0.y; myM[2] = m0.z; myM[3] = m0.w;
            myM[4] = m1.x; myM[5] = m1.y; myM[6] = m1.z; myM[7] = m1.w;
            myM[8] = m2.x;
        }
    }

    // ---------- Polar (fp64, proven) on this lane's sample ----------
    double X[9];
    polar3x3(myM, X);

    const long long samp = base + 16 * ((lane >> 2) & 3) + 4 * (lane >> 4) + (lane & 3);
    float* o = out + samp * 9;
    #pragma unroll
    for (int r = 0; r < 9; ++r) o[r] = (float)X[r];
}

// ---------- Fallback: proven R6-style 1 thread/sample VALU kernel ----------
__global__ __launch_bounds__(256) void pose_simple(
    const float* __restrict__ x,
    const float* __restrict__ w1, const float* __restrict__ b1,
    const float* __restrict__ w2, const float* __restrict__ b2,
    const float* __restrict__ w3, const float* __restrict__ b3,
    float* __restrict__ out, int nB)
{
    int tid = blockIdx.x * blockDim.x + threadIdx.x;
    if (tid >= nB) return;
    const float* xrow = x + (size_t)tid * ZDIM;

    float h1[HDIM];
    #pragma unroll
    for (int j = 0; j < HDIM; ++j) h1[j] = b1[j];
    #pragma unroll 1
    for (int k = 0; k < ZDIM; ++k) {
        float xv = xrow[k];
        #pragma unroll
        for (int j = 0; j < HDIM; ++j)
            h1[j] = fmaf(xv, w1[(size_t)j * ZDIM + k], h1[j]);
    }
    #pragma unroll
    for (int j = 0; j < HDIM; ++j) h1[j] = fmaxf(h1[j], 0.0f);

    float mr[9];
    #pragma unroll
    for (int r = 0; r < 9; ++r) mr[r] = b3[r];
    #pragma unroll 1
    for (int i = 0; i < HDIM; ++i) {
        const float* w2row = w2 + (size_t)i * HDIM;
        float a0 = 0.f, a1 = 0.f, a2 = 0.f, a3 = 0.f;
        #pragma unroll
        for (int j = 0; j < HDIM; j += 4) {
            a0 = fmaf(w2row[j + 0], h1[j + 0], a0);
            a1 = fmaf(w2row[j + 1], h1[j + 1], a1);
            a2 = fmaf(w2row[j + 2], h1[j + 2], a2);
            a3 = fmaf(w2row[j + 3], h1[j + 3], a3);
        }
        float tv = fast_tanh((a0 + a1) + (a2 + a3) + b2[i]);
        #pragma unroll
        for (int r = 0; r < 9; ++r)
            mr[r] = fmaf(w3[(size_t)r * HDIM + i], tv, mr[r]);
    }

    double X[9];
    polar3x3(mr, X);
    float* o = out + (size_t)tid * 9;
    #pragma unroll
    for (int r = 0; r < 9; ++r) o[r] = (float)X[r];
}

extern "C" void kernel_launch(void* const* d_in, const int* in_sizes, int n_in,
                              void* d_out, int out_size, void* d_ws, size_t ws_size,
                              hipStream_t stream) {
    const float* x  = (const float*)d_in[0];
    const float* w1 = (const float*)d_in[1];
    const float* b1 = (const float*)d_in[2];
    const float* w2 = (const float*)d_in[3];
    const float* b2 = (const float*)d_in[4];
    const float* w3 = (const float*)d_in[5];
    const float* b3 = (const float*)d_in[6];
    float* out = (float*)d_out;

    int nB = in_sizes[0] / ZDIM;

    // ws layout (bytes)
    const size_t off_w2p = (size_t)3 * NPW * sizeof(unsigned short);   // 86016
    const size_t off_w3b = off_w2p * 2;                                // 172032
    const size_t off_b1p = off_w3b + (size_t)3 * W3N * sizeof(unsigned short); // +12288
    const size_t off_b2p = off_b1p + 112 * sizeof(float);
    const size_t off_b3p = off_b2p + 112 * sizeof(float);
    const size_t need    = off_b3p + 16 * sizeof(float);

    if (ws_size >= need && (nB % 256) == 0) {
        unsigned short* w1p = (unsigned short*)d_ws;
        unsigned short* w2p = (unsigned short*)((char*)d_ws + off_w2p);
        unsigned short* w3b = (unsigned short*)((char*)d_ws + off_w3b);
        float* b1p = (float*)((char*)d_ws + off_b1p);
        float* b2p = (float*)((char*)d_ws + off_b2p);
        float* b3p = (float*)((char*)d_ws + off_b3p);

        prep_split<<<(NPW + 255) / 256, 256, 0, stream>>>(w1, w2, w3, b1, b2, b3,
                                                          w1p, w2p, w3b, b1p, b2p, b3p);
        dim3 grid(nB / 256);   // 1024 blocks; 4 waves/block; 64 samples/wave
        pose_mfma<<<grid, 256, 0, stream>>>(x, w1p, w2p, w3b, b1p, b2p, b3p, out);
    } else {
        dim3 grid((nB + 255) / 256);
        pose_simple<<<grid, 256, 0, stream>>>(x, w1, b1, w2, b2, w3, b3, out, nB);
    }
}